// Round 4
// baseline (105.608 us; speedup 1.0000x reference)
//
#include <hip/hip_runtime.h>

#define PAGE_SHIFT 4
#define PAGE_MASK 15

// ---------------- Kernel 1: dual exclusive prefix sum over B elements ----------------
// starts[i]    = sum_{j<i} (seq[j] - pre[j])
// new_start[i] = sum_{j<i} (ceil(seq[j]/16) - ceil(pre[j]/16))
__global__ __launch_bounds__(1024) void scan_kernel(const int* __restrict__ pre_lens,
                                                    const int* __restrict__ seq_lens,
                                                    int B,
                                                    int* __restrict__ starts,
                                                    int* __restrict__ new_start) {
    __shared__ int w_e[16];
    __shared__ int w_n[16];
    const int t = threadIdx.x;
    const int lane = t & 63;
    const int wv = t >> 6;
    const int i0 = t * 4;

    int pe[4], se[4];
    if (i0 + 3 < B) {
        int4 pv = *reinterpret_cast<const int4*>(pre_lens + i0);
        int4 sv = *reinterpret_cast<const int4*>(seq_lens + i0);
        pe[0] = pv.x; pe[1] = pv.y; pe[2] = pv.z; pe[3] = pv.w;
        se[0] = sv.x; se[1] = sv.y; se[2] = sv.z; se[3] = sv.w;
    } else {
#pragma unroll
        for (int j = 0; j < 4; ++j) {
            pe[j] = (i0 + j < B) ? pre_lens[i0 + j] : 0;
            se[j] = (i0 + j < B) ? seq_lens[i0 + j] : 0;
        }
    }

    int e[4], np[4];
    int tot_e = 0, tot_n = 0;
#pragma unroll
    for (int j = 0; j < 4; ++j) {
        e[j] = se[j] - pe[j];
        int pb = (pe[j] + PAGE_MASK) >> PAGE_SHIFT;
        int pa = (se[j] + PAGE_MASK) >> PAGE_SHIFT;
        np[j] = pa - pb;
        tot_e += e[j];
        tot_n += np[j];
    }

    // wave-64 inclusive scan of per-thread totals
    int sc_e = tot_e, sc_n = tot_n;
#pragma unroll
    for (int d = 1; d < 64; d <<= 1) {
        int ve = __shfl_up(sc_e, d, 64);
        int vn = __shfl_up(sc_n, d, 64);
        if (lane >= d) { sc_e += ve; sc_n += vn; }
    }
    if (lane == 63) { w_e[wv] = sc_e; w_n[wv] = sc_n; }
    __syncthreads();

    // wave 0 scans the 16 wave totals (inclusive)
    if (wv == 0) {
        int ve = (lane < 16) ? w_e[lane] : 0;
        int vn = (lane < 16) ? w_n[lane] : 0;
#pragma unroll
        for (int d = 1; d < 16; d <<= 1) {
            int ae = __shfl_up(ve, d, 64);
            int an = __shfl_up(vn, d, 64);
            if (lane >= d) { ve += ae; vn += an; }
        }
        if (lane < 16) { w_e[lane] = ve; w_n[lane] = vn; }
    }
    __syncthreads();

    int base_e = (wv > 0 ? w_e[wv - 1] : 0) + (sc_e - tot_e);  // exclusive base for this thread
    int base_n = (wv > 0 ? w_n[wv - 1] : 0) + (sc_n - tot_n);

    if (i0 + 3 < B) {
        int4 oe, on;
        oe.x = base_e;            on.x = base_n;
        oe.y = oe.x + e[0];       on.y = on.x + np[0];
        oe.z = oe.y + e[1];       on.z = on.y + np[1];
        oe.w = oe.z + e[2];       on.w = on.z + np[2];
        *reinterpret_cast<int4*>(starts + i0) = oe;
        *reinterpret_cast<int4*>(new_start + i0) = on;
    } else {
#pragma unroll
        for (int j = 0; j < 4; ++j) {
            if (i0 + j < B) { starts[i0 + j] = base_e; new_start[i0 + j] = base_n; }
            base_e += e[j];
            base_n += np[j];
        }
    }
}

// ---------------- Kernel 2: slot assignment ----------------
// Generic scalar path (head peel + tails).
__device__ __forceinline__ int slot_value(int o, int pre, int boundary, int pb, int ll1,
                                          int ns, const int* __restrict__ fp, int n_free) {
    int p = pre + o;
    if (p < boundary) return ll1 + o;                 // fill existing partial page
    int idx = ns + (p >> PAGE_SHIFT) - pb;            // which new page
    idx = min(max(idx, 0), n_free - 1);               // match reference clip
    return fp[idx] * (1 << PAGE_SHIFT) + (p & PAGE_MASK);
}

#define TOK_PER_THREAD 16
#define TOK_PER_BLOCK (256 * TOK_PER_THREAD)   // 4096 tokens / block

__global__ __launch_bounds__(256) void assign_kernel(const int* __restrict__ pre_lens,
                                                     const int* __restrict__ seq_lens,
                                                     const int* __restrict__ last_loc,
                                                     const int* __restrict__ free_page,
                                                     const int* __restrict__ starts,
                                                     const int* __restrict__ new_start,
                                                     int* __restrict__ out,
                                                     int n_free) {
    const int b = blockIdx.x;
    const int pre = pre_lens[b];
    const int ext = seq_lens[b] - pre;
    const int start = starts[b];
    const int al = (-start) & 3;               // head tokens so start+al is 16B-aligned
    const int ty = blockIdx.y;
    const int ll1 = last_loc[b] + 1;
    const int pb = (pre + PAGE_MASK) >> PAGE_SHIFT;
    const int boundary = pb << PAGE_SHIFT;
    const int ns = new_start[b];

    // head peel (<4 tokens), by ty==0 only
    if (ty == 0) {
        int t = (int)threadIdx.x;
        if (t < al && t < ext) {
            out[start + t] = slot_value(t, pre, boundary, pb, ll1, ns, free_page, n_free);
        }
    }

    const int stride = (int)gridDim.y * TOK_PER_BLOCK;
    for (int obase = al + ty * TOK_PER_BLOCK; obase < ext; obase += stride) {
        const int o0 = obase + (int)threadIdx.x * TOK_PER_THREAD;
        if (o0 >= ext) break;

        // 16 consecutive tokens span at most 2 pages: hoist the free_page loads.
        const int p0 = pre + o0;
        const int c = p0 & PAGE_MASK;                 // phase within page A
        const int pageA = p0 >> PAGE_SHIFT;
        int idxA = ns + pageA - pb;
        int idxB = idxA + 1;
        idxA = min(max(idxA, 0), n_free - 1);
        idxB = min(max(idxB, 0), n_free - 1);
        const int baseA = free_page[idxA] << PAGE_SHIFT;
        const int baseB = free_page[idxB] << PAGE_SHIFT;
        const bool p1A = pageA < pb;                  // page A entirely part1
        const bool p1B = (pageA + 1) < pb;            // page B entirely part1

        if (o0 + TOK_PER_THREAD - 1 < ext) {
            int vals[TOK_PER_THREAD];
#pragma unroll
            for (int j = 0; j < TOK_PER_THREAD; ++j) {
                int cj = c + j;
                bool inB = cj >= 16;
                bool part1 = inB ? p1B : p1A;
                int v2 = (inB ? baseB : baseA) + (cj & PAGE_MASK);
                vals[j] = part1 ? (ll1 + o0 + j) : v2;
            }
            int4* dst = reinterpret_cast<int4*>(out + start + o0);  // 16B-aligned
#pragma unroll
            for (int q = 0; q < 4; ++q) {
                dst[q] = make_int4(vals[4 * q], vals[4 * q + 1],
                                   vals[4 * q + 2], vals[4 * q + 3]);
            }
        } else {
            for (int o = o0; o < ext; ++o) {
                out[start + o] = slot_value(o, pre, boundary, pb, ll1, ns, free_page, n_free);
            }
        }
    }
}

extern "C" void kernel_launch(void* const* d_in, const int* in_sizes, int n_in,
                              void* d_out, int out_size, void* d_ws, size_t ws_size,
                              hipStream_t stream) {
    const int* pre_lens  = (const int*)d_in[0];
    const int* seq_lens  = (const int*)d_in[1];
    const int* last_loc  = (const int*)d_in[2];
    const int* free_page = (const int*)d_in[3];
    const int B = in_sizes[0];
    const int n_free = in_sizes[3];

    int* starts    = (int*)d_ws;            // B ints
    int* new_start = ((int*)d_ws) + B;      // B ints

    scan_kernel<<<1, 1024, 0, stream>>>(pre_lens, seq_lens, B, starts, new_start);
    dim3 grid(B, 2);                        // 2 tiles x 4096 tokens covers ext < 8192 (+loop guard)
    assign_kernel<<<grid, 256, 0, stream>>>(pre_lens, seq_lens, last_loc, free_page,
                                            starts, new_start, (int*)d_out, n_free);
}